// Round 3
// baseline (562.273 us; speedup 1.0000x reference)
//
#include <hip/hip_runtime.h>

#define B_ 8
#define L_ 128
#define D_ 512
#define H_ 8

__device__ __forceinline__ float leaky(float v) { return fmaxf(v, 0.2f * v); }

// ---------------------------------------------------------------------------
// K1: Wr_eff[k][h] = sum_d W_relation[k][h*64+d] * w_rel[h][d]   (512 x 8 fp32)
// ---------------------------------------------------------------------------
__global__ __launch_bounds__(256) void k_wreff(const float* __restrict__ Wrel,
                                               const float* __restrict__ wrel,
                                               float* __restrict__ wr_eff) {
    int t = blockIdx.x * 256 + threadIdx.x;   // 0..4095
    int k = t >> 3, h = t & 7;
    const float4* a = (const float4*)(Wrel + k * 512 + h * 64);
    const float4* b = (const float4*)(wrel + h * 64);
    float acc = 0.f;
#pragma unroll
    for (int q = 0; q < 16; q++) {
        float4 av = a[q], bv = b[q];
        acc += av.x * bv.x + av.y * bv.y + av.z * bv.z + av.w * bv.w;
    }
    wr_eff[k * 8 + h] = acc;
}

// ---------------------------------------------------------------------------
// K2: s_rel[b][h][i][j] = leaky( rel[b,i,j,:] . Wr_eff[:,h] )
// One 64-lane wave per row; lane holds k=lane*8..+7; butterfly allreduce.
// Compile-time 16-row trip count so loads software-pipeline.
// Output written into the attn_relation region of d_out (overwritten later
// by k_attn with the final attention — same-thread read-then-write, safe).
// ---------------------------------------------------------------------------
__global__ __launch_bounds__(256) void k_srel(const float* __restrict__ rel,
                                              const float* __restrict__ wr_eff,
                                              float* __restrict__ s_rel) {
    const int lane = threadIdx.x & 63;
    const int wave = (blockIdx.x * 256 + threadIdx.x) >> 6;   // 0..8191

    float wrl[64];   // wrl[kk*8+h] = wr_eff[(lane*8+kk)*8+h]
    {
        const float4* wp = (const float4*)(wr_eff + lane * 64);
#pragma unroll
        for (int q = 0; q < 16; q++) {
            float4 v = wp[q];
            wrl[q * 4 + 0] = v.x; wrl[q * 4 + 1] = v.y;
            wrl[q * 4 + 2] = v.z; wrl[q * 4 + 3] = v.w;
        }
    }

#pragma unroll 2
    for (int it = 0; it < 16; ++it) {
        int row = wave + it * 8192;
        const float4* rp = (const float4*)(rel + (size_t)row * 512 + lane * 8);
        float4 u0 = rp[0];
        float4 u1 = rp[1];
        float x[8];
        x[0] = u0.x; x[1] = u0.y; x[2] = u0.z; x[3] = u0.w;
        x[4] = u1.x; x[5] = u1.y; x[6] = u1.z; x[7] = u1.w;
        float acc[8] = {0.f,0.f,0.f,0.f,0.f,0.f,0.f,0.f};
#pragma unroll
        for (int kk = 0; kk < 8; kk++)
#pragma unroll
            for (int h = 0; h < 8; h++)
                acc[h] = fmaf(x[kk], wrl[kk * 8 + h], acc[h]);
#pragma unroll
        for (int off = 32; off >= 1; off >>= 1)
#pragma unroll
            for (int h = 0; h < 8; h++)
                acc[h] += __shfl_xor(acc[h], off, 64);
        if (lane < 8) {
            float v = acc[0];
#pragma unroll
            for (int h = 1; h < 8; h++) v = (lane == h) ? acc[h] : v;
            v = leaky(v);
            int b = row >> 14, rem = row & 16383;   // rem = i*128 + j
            s_rel[(((size_t)(b * 8 + lane)) << 14) + rem] = v;
        }
    }
}

// ---------------------------------------------------------------------------
// K3: value_t[b][h][d][l] = (inp @ W_value)[b,l,h*64+d]  (fp32, transposed)
//     e_src[b,h,l], e_tgt[b,h,l] fused.
// Block: 4 rows (b,l) x 512 cols; thread owns cols 2t, 2t+1.
// ---------------------------------------------------------------------------
__global__ __launch_bounds__(256) void k_value(const float* __restrict__ inp,
                                               const float* __restrict__ Wv,
                                               const float* __restrict__ wsrc,
                                               const float* __restrict__ wtgt,
                                               float* __restrict__ value_t,
                                               float* __restrict__ e_src,
                                               float* __restrict__ e_tgt) {
    __shared__ float xs[4][512];
    const int t = threadIdx.x;
    const int row0 = blockIdx.x * 4;           // flat b*128+l
    {
        int r = t >> 6, seg = t & 63;
        const float4* ip = (const float4*)(inp + (size_t)(row0 + r) * 512 + seg * 8);
        float4 a = ip[0], bq = ip[1];
        *(float4*)&xs[r][seg * 8]     = a;
        *(float4*)&xs[r][seg * 8 + 4] = bq;
    }
    __syncthreads();
    const int c0 = t * 2;
    float acc[4][2] = {};
    for (int k0 = 0; k0 < 512; k0 += 4) {
        float4 xr[4];
#pragma unroll
        for (int r = 0; r < 4; r++) xr[r] = *(const float4*)&xs[r][k0];
#define VSTEP(COMP, I)                                                          \
        {                                                                       \
            float2 wv = *(const float2*)(Wv + (size_t)(k0 + I) * 512 + c0);     \
            _Pragma("unroll")                                                   \
            for (int r = 0; r < 4; r++) {                                       \
                acc[r][0] = fmaf(xr[r].COMP, wv.x, acc[r][0]);                  \
                acc[r][1] = fmaf(xr[r].COMP, wv.y, acc[r][1]);                  \
            }                                                                   \
        }
        VSTEP(x, 0) VSTEP(y, 1) VSTEP(z, 2) VSTEP(w, 3)
#undef VSTEP
    }
    const int h = t >> 5;          // c0/64
    const int d0 = c0 & 63;
    const int b = row0 >> 7, l0 = row0 & 127;
    {
        float4 v0 = make_float4(acc[0][0], acc[1][0], acc[2][0], acc[3][0]);
        float4 v1 = make_float4(acc[0][1], acc[1][1], acc[2][1], acc[3][1]);
        *(float4*)&value_t[((size_t)((b * 8 + h) * 64 + d0)) * 128 + l0] = v0;
        *(float4*)&value_t[((size_t)((b * 8 + h) * 64 + d0 + 1)) * 128 + l0] = v1;
    }
    float ws0 = wsrc[c0], ws1 = wsrc[c0 + 1];
    float wt0 = wtgt[c0], wt1 = wtgt[c0 + 1];
    float es[4], et[4];
#pragma unroll
    for (int r = 0; r < 4; r++) {
        es[r] = acc[r][0] * ws0 + acc[r][1] * ws1;
        et[r] = acc[r][0] * wt0 + acc[r][1] * wt1;
    }
#pragma unroll
    for (int off = 16; off >= 1; off >>= 1)
#pragma unroll
        for (int r = 0; r < 4; r++) {
            es[r] += __shfl_xor(es[r], off, 64);
            et[r] += __shfl_xor(et[r], off, 64);
        }
    if ((t & 31) == 0) {
#pragma unroll
        for (int r = 0; r < 4; r++) {
            e_src[(b * 8 + h) * 128 + l0 + r] = es[r];
            e_tgt[(b * 8 + h) * 128 + l0 + r] = et[r];
        }
    }
}

// ---------------------------------------------------------------------------
// K4: fused masked softmax (both attentions) + attn @ V.
// Block = one (b,h) + 4 i-rows (one per wave).
// No value LDS tile: lane d streams its own 512 B global value row (L1/L2
// resident — value_t is 2 MB total, 32 KB per bh shared by all 4 waves);
// attention weights come from LDS as wave-uniform b128 broadcasts
// (conflict-free). LDS = 4 KB -> 8 blocks/CU.
// ---------------------------------------------------------------------------
__global__ __launch_bounds__(256) void k_attn(const float* s_rel,
                                              const float* __restrict__ value_t,
                                              const float* __restrict__ e_src,
                                              const float* __restrict__ e_tgt,
                                              const int* __restrict__ adj,
                                              const unsigned char* __restrict__ mask,
                                              float* __restrict__ X,
                                              float* __restrict__ out_av,
                                              float* out_ar) {
    __shared__ float lav[4][128];
    __shared__ float lar[4][128];
    const int t = threadIdx.x;
    const int bh = blockIdx.x >> 5;        // 0..63
    const int iq = blockIdx.x & 31;
    const int b = bh >> 3;

    const int lane = t & 63;
    const int w = t >> 6;
    const int i = iq * 4 + w;
    const size_t rowbase = ((size_t)bh * 128 + i) * 128;
    const float etg = e_tgt[bh * 128 + i];
    const int j0 = lane, j1 = lane + 64;

    float sv0 = leaky(etg + e_src[bh * 128 + j0]);
    float sv1 = leaky(etg + e_src[bh * 128 + j1]);
    float sr0 = s_rel[rowbase + j0];
    float sr1 = s_rel[rowbase + j1];
    int a0 = adj[rowbase + j0], a1 = adj[rowbase + j1];
    unsigned char m0 = mask[(size_t)(b * 128 + i) * 128 + j0];
    unsigned char m1 = mask[(size_t)(b * 128 + i) * 128 + j1];
    bool bad0 = m0 || (a0 == 0);
    bool bad1 = m1 || (a1 == 0);
    if (bad0) { sv0 = -1e30f; sr0 = -1e30f; }
    if (bad1) { sv1 = -1e30f; sr1 = -1e30f; }

    float mv = fmaxf(sv0, sv1), mr = fmaxf(sr0, sr1);
#pragma unroll
    for (int off = 32; off >= 1; off >>= 1) {
        mv = fmaxf(mv, __shfl_xor(mv, off, 64));
        mr = fmaxf(mr, __shfl_xor(mr, off, 64));
    }
    float pv0 = bad0 ? 0.f : __expf(sv0 - mv);
    float pv1 = bad1 ? 0.f : __expf(sv1 - mv);
    float pr0 = bad0 ? 0.f : __expf(sr0 - mr);
    float pr1 = bad1 ? 0.f : __expf(sr1 - mr);
    float sumv = pv0 + pv1, sumr = pr0 + pr1;
#pragma unroll
    for (int off = 32; off >= 1; off >>= 1) {
        sumv += __shfl_xor(sumv, off, 64);
        sumr += __shfl_xor(sumr, off, 64);
    }
    float iv = 1.f / fmaxf(sumv, 1e-12f);
    float ir = 1.f / fmaxf(sumr, 1e-12f);
    float av0 = pv0 * iv, av1 = pv1 * iv;
    float ar0 = pr0 * ir, ar1 = pr1 * ir;

    out_av[rowbase + j0] = av0;
    out_av[rowbase + j1] = av1;
    out_ar[rowbase + j0] = ar0;
    out_ar[rowbase + j1] = ar1;

    lav[w][j0] = av0; lav[w][j1] = av1;
    lar[w][j0] = ar0; lar[w][j1] = ar1;
    __syncthreads();

    // attn @ V : lane owns d = lane; stream global value row (L1/L2 hot).
    const float4* vrow = (const float4*)(value_t + ((size_t)bh * 64 + lane) * 128);
    float accv = 0.f, accr = 0.f;
#pragma unroll 8
    for (int jb = 0; jb < 32; jb++) {
        float4 v4 = vrow[jb];
        float4 a4 = *(const float4*)&lav[w][jb * 4];
        float4 r4 = *(const float4*)&lar[w][jb * 4];
        accv = fmaf(a4.x, v4.x, accv); accv = fmaf(a4.y, v4.y, accv);
        accv = fmaf(a4.z, v4.z, accv); accv = fmaf(a4.w, v4.w, accv);
        accr = fmaf(r4.x, v4.x, accr); accr = fmaf(r4.y, v4.y, accr);
        accr = fmaf(r4.z, v4.z, accr); accr = fmaf(r4.w, v4.w, accr);
    }
    const int hh = bh & 7;
    size_t xrow = ((size_t)(b * 128 + i)) * 1024;
    X[xrow + hh * 64 + lane] = accv;
    X[xrow + 512 + hh * 64 + lane] = accr;
}

// ---------------------------------------------------------------------------
// K5: final = X @ W_final + b_final + inp   (X fp32 1024x1024, Wf fp32 1024x512)
// ---------------------------------------------------------------------------
__global__ __launch_bounds__(256) void k_final(const float* __restrict__ X,
                                               const float* __restrict__ Wf,
                                               const float* __restrict__ bias,
                                               const float* __restrict__ inp,
                                               float* __restrict__ outf) {
    __shared__ float xs[4][1024];
    const int t = threadIdx.x;
    const int row0 = blockIdx.x * 4;
    {
        const float4* src = (const float4*)(X + (size_t)row0 * 1024);
        float4* dst = (float4*)xs;
#pragma unroll
        for (int q = 0; q < 4; q++) dst[q * 256 + t] = src[q * 256 + t];
    }
    __syncthreads();
    const int c0 = t * 2;
    float acc[4][2] = {};
    for (int k0 = 0; k0 < 1024; k0 += 4) {
        float4 xr[4];
#pragma unroll
        for (int r = 0; r < 4; r++) xr[r] = *(const float4*)&xs[r][k0];
#define FSTEP(COMP, I)                                                          \
        {                                                                       \
            float2 wv = *(const float2*)(Wf + (size_t)(k0 + I) * 512 + c0);     \
            _Pragma("unroll")                                                   \
            for (int r = 0; r < 4; r++) {                                       \
                acc[r][0] = fmaf(xr[r].COMP, wv.x, acc[r][0]);                  \
                acc[r][1] = fmaf(xr[r].COMP, wv.y, acc[r][1]);                  \
            }                                                                   \
        }
        FSTEP(x, 0) FSTEP(y, 1) FSTEP(z, 2) FSTEP(w, 3)
#undef FSTEP
    }
    float b0 = bias[c0], b1 = bias[c0 + 1];
#pragma unroll
    for (int r = 0; r < 4; r++) {
        size_t ro = (size_t)(row0 + r) * 512;
        float2 iv = *(const float2*)(inp + ro + c0);
        float v0 = acc[r][0] + b0 + iv.x;
        float v1 = acc[r][1] + b1 + iv.y;
        *(float2*)&outf[ro + c0] = make_float2(v0, v1);
    }
}

// ---------------------------------------------------------------------------
extern "C" void kernel_launch(void* const* d_in, const int* in_sizes, int n_in,
                              void* d_out, int out_size, void* d_ws, size_t ws_size,
                              hipStream_t stream) {
    const float* inp  = (const float*)d_in[0];
    const float* rel  = (const float*)d_in[1];
    const unsigned char* mask = (const unsigned char*)d_in[2];
    const int*   adj  = (const int*)d_in[3];
    const float* Wv   = (const float*)d_in[7];
    const float* Wr   = (const float*)d_in[8];
    const float* wsrc = (const float*)d_in[9];
    const float* wtgt = (const float*)d_in[10];
    const float* wrel = (const float*)d_in[11];
    const float* Wf   = (const float*)d_in[12];
    const float* bfin = (const float*)d_in[13];

    float* outf   = (float*)d_out;
    float* out_av = outf + (size_t)B_ * L_ * D_;                 // +524288
    float* out_ar = out_av + (size_t)B_ * H_ * L_ * L_;          // +1048576

    char* ws = (char*)d_ws;
    float* wr_eff  = (float*)(ws);                       // 16 KB
    float* value_t = (float*)(ws + 16384);               // 2 MB
    float* e_src   = (float*)(ws + 2113536);             // 32 KB
    float* e_tgt   = (float*)(ws + 2146304);             // 32 KB
    float* X       = (float*)(ws + 2179072);             // 4 MB (ends ~6.1 MB)

    k_wreff<<<16, 256, 0, stream>>>(Wr, wrel, wr_eff);
    k_value<<<256, 256, 0, stream>>>(inp, Wv, wsrc, wtgt, value_t, e_src, e_tgt);
    k_srel<<<2048, 256, 0, stream>>>(rel, wr_eff, out_ar);      // scores staged in out_ar
    k_attn<<<2048, 256, 0, stream>>>(out_ar, value_t, e_src, e_tgt, adj, mask,
                                     X, out_av, out_ar);
    k_final<<<256, 256, 0, stream>>>(X, Wf, bfin, inp, outf);
}

// Round 4
// 550.514 us; speedup vs baseline: 1.0214x; 1.0214x over previous
//
#include <hip/hip_runtime.h>

#define B_ 8
#define L_ 128
#define D_ 512
#define H_ 8

__device__ __forceinline__ float leaky(float v) { return fmaxf(v, 0.2f * v); }

// ---------------------------------------------------------------------------
// K3+K1 merged: blocks 0..255 = value GEMM (+e_src/e_tgt), blocks 256..271 =
// Wr_eff[k][h] = sum_d W_relation[k][h*64+d]*w_rel[h][d].
// ---------------------------------------------------------------------------
__global__ __launch_bounds__(256) void k_value_wreff(
        const float* __restrict__ inp, const float* __restrict__ Wv,
        const float* __restrict__ wsrc, const float* __restrict__ wtgt,
        const float* __restrict__ Wrel, const float* __restrict__ wrel,
        float* __restrict__ value_t, float* __restrict__ e_src,
        float* __restrict__ e_tgt, float* __restrict__ wr_eff) {
    __shared__ float xs[4][512];
    const int t = threadIdx.x;

    if (blockIdx.x >= 256) {               // ---- wreff part ----
        int g = (blockIdx.x - 256) * 256 + t;   // 0..4095
        int k = g >> 3, h = g & 7;
        const float4* a = (const float4*)(Wrel + k * 512 + h * 64);
        const float4* b = (const float4*)(wrel + h * 64);
        float acc = 0.f;
#pragma unroll
        for (int q = 0; q < 16; q++) {
            float4 av = a[q], bv = b[q];
            acc += av.x * bv.x + av.y * bv.y + av.z * bv.z + av.w * bv.w;
        }
        wr_eff[k * 8 + h] = acc;
        return;
    }

    const int row0 = blockIdx.x * 4;           // flat b*128+l
    {
        int r = t >> 6, seg = t & 63;
        const float4* ip = (const float4*)(inp + (size_t)(row0 + r) * 512 + seg * 8);
        float4 a = ip[0], bq = ip[1];
        *(float4*)&xs[r][seg * 8]     = a;
        *(float4*)&xs[r][seg * 8 + 4] = bq;
    }
    __syncthreads();
    const int c0 = t * 2;
    float acc[4][2] = {};
    for (int k0 = 0; k0 < 512; k0 += 4) {
        float4 xr[4];
#pragma unroll
        for (int r = 0; r < 4; r++) xr[r] = *(const float4*)&xs[r][k0];
#define VSTEP(COMP, I)                                                          \
        {                                                                       \
            float2 wv = *(const float2*)(Wv + (size_t)(k0 + I) * 512 + c0);     \
            _Pragma("unroll")                                                   \
            for (int r = 0; r < 4; r++) {                                       \
                acc[r][0] = fmaf(xr[r].COMP, wv.x, acc[r][0]);                  \
                acc[r][1] = fmaf(xr[r].COMP, wv.y, acc[r][1]);                  \
            }                                                                   \
        }
        VSTEP(x, 0) VSTEP(y, 1) VSTEP(z, 2) VSTEP(w, 3)
#undef VSTEP
    }
    const int h = t >> 5;          // c0/64
    const int d0 = c0 & 63;
    const int b = row0 >> 7, l0 = row0 & 127;
    {
        float4 v0 = make_float4(acc[0][0], acc[1][0], acc[2][0], acc[3][0]);
        float4 v1 = make_float4(acc[0][1], acc[1][1], acc[2][1], acc[3][1]);
        *(float4*)&value_t[((size_t)((b * 8 + h) * 64 + d0)) * 128 + l0] = v0;
        *(float4*)&value_t[((size_t)((b * 8 + h) * 64 + d0 + 1)) * 128 + l0] = v1;
    }
    float ws0 = wsrc[c0], ws1 = wsrc[c0 + 1];
    float wt0 = wtgt[c0], wt1 = wtgt[c0 + 1];
    float es[4], et[4];
#pragma unroll
    for (int r = 0; r < 4; r++) {
        es[r] = acc[r][0] * ws0 + acc[r][1] * ws1;
        et[r] = acc[r][0] * wt0 + acc[r][1] * wt1;
    }
#pragma unroll
    for (int off = 16; off >= 1; off >>= 1)
#pragma unroll
        for (int r = 0; r < 4; r++) {
            es[r] += __shfl_xor(es[r], off, 64);
            et[r] += __shfl_xor(et[r], off, 64);
        }
    if ((t & 31) == 0) {
#pragma unroll
        for (int r = 0; r < 4; r++) {
            e_src[(b * 8 + h) * 128 + l0 + r] = es[r];
            e_tgt[(b * 8 + h) * 128 + l0 + r] = et[r];
        }
    }
}

// ---------------------------------------------------------------------------
// K2: s_rel[b][h][i][j] = leaky( rel[b,i,j,:] . Wr_eff[:,h] )
// One 64-lane wave per row; lane holds k=lane*8..+7.
// Register-halving reduction: 10 shuffles/row instead of 48.
//   xor32 keeps 4 accs (half-wave owns h0-3 / h4-7), xor16 -> 2, xor8 -> 1;
//   lane l then holds partial for h=(l>>3)&7; finish with xor 4,2,1.
// ---------------------------------------------------------------------------
__global__ __launch_bounds__(256) void k_srel(const float* __restrict__ rel,
                                              const float* __restrict__ wr_eff,
                                              float* __restrict__ s_rel) {
    const int lane = threadIdx.x & 63;
    const int wave = (blockIdx.x * 256 + threadIdx.x) >> 6;   // 0..8191

    float wrl[64];   // wrl[kk*8+h] = wr_eff[(lane*8+kk)*8+h]
    {
        const float4* wp = (const float4*)(wr_eff + lane * 64);
#pragma unroll
        for (int q = 0; q < 16; q++) {
            float4 v = wp[q];
            wrl[q * 4 + 0] = v.x; wrl[q * 4 + 1] = v.y;
            wrl[q * 4 + 2] = v.z; wrl[q * 4 + 3] = v.w;
        }
    }

    const bool hi32 = (lane & 32) != 0;
    const bool hi16 = (lane & 16) != 0;
    const bool hi8  = (lane & 8) != 0;
    const int  hsel = (lane >> 3) & 7;     // head this lane ends up owning

#pragma unroll 2
    for (int it = 0; it < 16; ++it) {
        int row = wave + it * 8192;
        const float4* rp = (const float4*)(rel + (size_t)row * 512 + lane * 8);
        float4 u0 = rp[0];
        float4 u1 = rp[1];
        float x[8];
        x[0] = u0.x; x[1] = u0.y; x[2] = u0.z; x[3] = u0.w;
        x[4] = u1.x; x[5] = u1.y; x[6] = u1.z; x[7] = u1.w;
        float acc[8] = {0.f,0.f,0.f,0.f,0.f,0.f,0.f,0.f};
#pragma unroll
        for (int kk = 0; kk < 8; kk++)
#pragma unroll
            for (int h = 0; h < 8; h++)
                acc[h] = fmaf(x[kk], wrl[kk * 8 + h], acc[h]);

        // xor 32: 8 accs -> 4
        float a4[4];
#pragma unroll
        for (int hh = 0; hh < 4; hh++) {
            float send = hi32 ? acc[hh] : acc[hh + 4];
            float recv = __shfl_xor(send, 32, 64);
            float own  = hi32 ? acc[hh + 4] : acc[hh];
            a4[hh] = own + recv;
        }
        // xor 16: 4 -> 2
        float a2[2];
#pragma unroll
        for (int hh = 0; hh < 2; hh++) {
            float send = hi16 ? a4[hh] : a4[hh + 2];
            float recv = __shfl_xor(send, 16, 64);
            float own  = hi16 ? a4[hh + 2] : a4[hh];
            a2[hh] = own + recv;
        }
        // xor 8: 2 -> 1
        float send = hi8 ? a2[0] : a2[1];
        float recv = __shfl_xor(send, 8, 64);
        float a1 = (hi8 ? a2[1] : a2[0]) + recv;
        // reduce remaining bits 0..2
        a1 += __shfl_xor(a1, 4, 64);
        a1 += __shfl_xor(a1, 2, 64);
        a1 += __shfl_xor(a1, 1, 64);

        if ((lane & 7) == 0) {
            float v = leaky(a1);
            int b = row >> 14, rem = row & 16383;   // rem = i*128 + j
            s_rel[(((size_t)(b * 8 + hsel)) << 14) + rem] = v;
        }
    }
}

// ---------------------------------------------------------------------------
// K4: fused masked softmax (both attentions) + attn @ V.
// Block = one (b,h) + 4 i-rows (one per wave). Value rows streamed from
// global (value_t 2 MB, L2-resident); attention weights via LDS wave-uniform
// b128 broadcasts. s_rel aliases out_ar (same-thread read-then-write).
// ---------------------------------------------------------------------------
__global__ __launch_bounds__(256) void k_attn(const float* s_rel,
                                              const float* __restrict__ value_t,
                                              const float* __restrict__ e_src,
                                              const float* __restrict__ e_tgt,
                                              const int* __restrict__ adj,
                                              const unsigned char* __restrict__ mask,
                                              float* __restrict__ X,
                                              float* __restrict__ out_av,
                                              float* out_ar) {
    __shared__ float lav[4][128];
    __shared__ float lar[4][128];
    const int t = threadIdx.x;
    const int bh = blockIdx.x >> 5;        // 0..63
    const int iq = blockIdx.x & 31;
    const int b = bh >> 3;

    const int lane = t & 63;
    const int w = t >> 6;
    const int i = iq * 4 + w;
    const size_t rowbase = ((size_t)bh * 128 + i) * 128;
    const float etg = e_tgt[bh * 128 + i];
    const int j0 = lane, j1 = lane + 64;

    float sv0 = leaky(etg + e_src[bh * 128 + j0]);
    float sv1 = leaky(etg + e_src[bh * 128 + j1]);
    float sr0 = s_rel[rowbase + j0];
    float sr1 = s_rel[rowbase + j1];
    int a0 = adj[rowbase + j0], a1 = adj[rowbase + j1];
    unsigned char m0 = mask[(size_t)(b * 128 + i) * 128 + j0];
    unsigned char m1 = mask[(size_t)(b * 128 + i) * 128 + j1];
    bool bad0 = m0 || (a0 == 0);
    bool bad1 = m1 || (a1 == 0);
    if (bad0) { sv0 = -1e30f; sr0 = -1e30f; }
    if (bad1) { sv1 = -1e30f; sr1 = -1e30f; }

    float mv = fmaxf(sv0, sv1), mr = fmaxf(sr0, sr1);
#pragma unroll
    for (int off = 32; off >= 1; off >>= 1) {
        mv = fmaxf(mv, __shfl_xor(mv, off, 64));
        mr = fmaxf(mr, __shfl_xor(mr, off, 64));
    }
    float pv0 = bad0 ? 0.f : __expf(sv0 - mv);
    float pv1 = bad1 ? 0.f : __expf(sv1 - mv);
    float pr0 = bad0 ? 0.f : __expf(sr0 - mr);
    float pr1 = bad1 ? 0.f : __expf(sr1 - mr);
    float sumv = pv0 + pv1, sumr = pr0 + pr1;
#pragma unroll
    for (int off = 32; off >= 1; off >>= 1) {
        sumv += __shfl_xor(sumv, off, 64);
        sumr += __shfl_xor(sumr, off, 64);
    }
    float iv = 1.f / fmaxf(sumv, 1e-12f);
    float ir = 1.f / fmaxf(sumr, 1e-12f);
    float av0 = pv0 * iv, av1 = pv1 * iv;
    float ar0 = pr0 * ir, ar1 = pr1 * ir;

    out_av[rowbase + j0] = av0;
    out_av[rowbase + j1] = av1;
    out_ar[rowbase + j0] = ar0;
    out_ar[rowbase + j1] = ar1;

    lav[w][j0] = av0; lav[w][j1] = av1;
    lar[w][j0] = ar0; lar[w][j1] = ar1;
    __syncthreads();

    const float4* vrow = (const float4*)(value_t + ((size_t)bh * 64 + lane) * 128);
    float accv = 0.f, accr = 0.f;
#pragma unroll 8
    for (int jb = 0; jb < 32; jb++) {
        float4 v4 = vrow[jb];
        float4 a4 = *(const float4*)&lav[w][jb * 4];
        float4 r4 = *(const float4*)&lar[w][jb * 4];
        accv = fmaf(a4.x, v4.x, accv); accv = fmaf(a4.y, v4.y, accv);
        accv = fmaf(a4.z, v4.z, accv); accv = fmaf(a4.w, v4.w, accv);
        accr = fmaf(r4.x, v4.x, accr); accr = fmaf(r4.y, v4.y, accr);
        accr = fmaf(r4.z, v4.z, accr); accr = fmaf(r4.w, v4.w, accr);
    }
    const int hh = bh & 7;
    size_t xrow = ((size_t)(b * 128 + i)) * 1024;
    X[xrow + hh * 64 + lane] = accv;
    X[xrow + 512 + hh * 64 + lane] = accr;
}

// ---------------------------------------------------------------------------
// K5: final = X @ W_final + b_final + inp   (X fp32 1024x1024, Wf fp32 1024x512)
// ---------------------------------------------------------------------------
__global__ __launch_bounds__(256) void k_final(const float* __restrict__ X,
                                               const float* __restrict__ Wf,
                                               const float* __restrict__ bias,
                                               const float* __restrict__ inp,
                                               float* __restrict__ outf) {
    __shared__ float xs[4][1024];
    const int t = threadIdx.x;
    const int row0 = blockIdx.x * 4;
    {
        const float4* src = (const float4*)(X + (size_t)row0 * 1024);
        float4* dst = (float4*)xs;
#pragma unroll
        for (int q = 0; q < 4; q++) dst[q * 256 + t] = src[q * 256 + t];
    }
    __syncthreads();
    const int c0 = t * 2;
    float acc[4][2] = {};
    for (int k0 = 0; k0 < 1024; k0 += 4) {
        float4 xr[4];
#pragma unroll
        for (int r = 0; r < 4; r++) xr[r] = *(const float4*)&xs[r][k0];
#define FSTEP(COMP, I)                                                          \
        {                                                                       \
            float2 wv = *(const float2*)(Wf + (size_t)(k0 + I) * 512 + c0);     \
            _Pragma("unroll")                                                   \
            for (int r = 0; r < 4; r++) {                                       \
                acc[r][0] = fmaf(xr[r].COMP, wv.x, acc[r][0]);                  \
                acc[r][1] = fmaf(xr[r].COMP, wv.y, acc[r][1]);                  \
            }                                                                   \
        }
        FSTEP(x, 0) FSTEP(y, 1) FSTEP(z, 2) FSTEP(w, 3)
#undef FSTEP
    }
    float b0 = bias[c0], b1 = bias[c0 + 1];
#pragma unroll
    for (int r = 0; r < 4; r++) {
        size_t ro = (size_t)(row0 + r) * 512;
        float2 iv = *(const float2*)(inp + ro + c0);
        float v0 = acc[r][0] + b0 + iv.x;
        float v1 = acc[r][1] + b1 + iv.y;
        *(float2*)&outf[ro + c0] = make_float2(v0, v1);
    }
}

// ---------------------------------------------------------------------------
extern "C" void kernel_launch(void* const* d_in, const int* in_sizes, int n_in,
                              void* d_out, int out_size, void* d_ws, size_t ws_size,
                              hipStream_t stream) {
    const float* inp  = (const float*)d_in[0];
    const float* rel  = (const float*)d_in[1];
    const unsigned char* mask = (const unsigned char*)d_in[2];
    const int*   adj  = (const int*)d_in[3];
    const float* Wv   = (const float*)d_in[7];
    const float* Wr   = (const float*)d_in[8];
    const float* wsrc = (const float*)d_in[9];
    const float* wtgt = (const float*)d_in[10];
    const float* wrel = (const float*)d_in[11];
    const float* Wf   = (const float*)d_in[12];
    const float* bfin = (const float*)d_in[13];

    float* outf   = (float*)d_out;
    float* out_av = outf + (size_t)B_ * L_ * D_;                 // +524288
    float* out_ar = out_av + (size_t)B_ * H_ * L_ * L_;          // +1048576

    char* ws = (char*)d_ws;
    float* wr_eff  = (float*)(ws);                       // 16 KB
    float* value_t = (float*)(ws + 16384);               // 2 MB
    float* e_src   = (float*)(ws + 2113536);             // 32 KB
    float* e_tgt   = (float*)(ws + 2146304);             // 32 KB
    float* X       = (float*)(ws + 2179072);             // 4 MB (ends ~6.1 MB)

    k_value_wreff<<<272, 256, 0, stream>>>(inp, Wv, wsrc, wtgt, Wr, wrel,
                                           value_t, e_src, e_tgt, wr_eff);
    k_srel<<<2048, 256, 0, stream>>>(rel, wr_eff, out_ar);      // scores staged in out_ar
    k_attn<<<2048, 256, 0, stream>>>(out_ar, value_t, e_src, e_tgt, adj, mask,
                                     X, out_av, out_ar);
    k_final<<<256, 256, 0, stream>>>(X, Wf, bfin, inp, outf);
}

// Round 5
// 536.046 us; speedup vs baseline: 1.0489x; 1.0270x over previous
//
#include <hip/hip_runtime.h>

#define B_ 8
#define L_ 128
#define D_ 512
#define H_ 8

__device__ __forceinline__ float leaky(float v) { return fmaxf(v, 0.2f * v); }

// ---------------------------------------------------------------------------
// K1: Wr_eff[k][h] = sum_d W_relation[k][h*64+d] * w_rel[h][d]   (512 x 8 fp32)
// ---------------------------------------------------------------------------
__global__ __launch_bounds__(256) void k_wreff(const float* __restrict__ Wrel,
                                               const float* __restrict__ wrel,
                                               float* __restrict__ wr_eff) {
    int t = blockIdx.x * 256 + threadIdx.x;   // 0..4095
    int k = t >> 3, h = t & 7;
    const float4* a = (const float4*)(Wrel + k * 512 + h * 64);
    const float4* b = (const float4*)(wrel + h * 64);
    float acc = 0.f;
#pragma unroll
    for (int q = 0; q < 16; q++) {
        float4 av = a[q], bv = b[q];
        acc += av.x * bv.x + av.y * bv.y + av.z * bv.z + av.w * bv.w;
    }
    wr_eff[k * 8 + h] = acc;
}

// ---------------------------------------------------------------------------
// K2: one launch, two block families (co-scheduled so the small value GEMM
// hides inside the srel HBM stream):
//   blocks 0..2047   : s_rel[b][h][i][j] = leaky(rel[b,i,j,:] . Wr_eff[:,h])
//   blocks 2048..2303: value_t GEMM + e_src/e_tgt
// ---------------------------------------------------------------------------
__global__ __launch_bounds__(256) void k_srel_value(
        const float* __restrict__ rel, const float* __restrict__ wr_eff,
        const float* __restrict__ inp, const float* __restrict__ Wv,
        const float* __restrict__ wsrc, const float* __restrict__ wtgt,
        float* __restrict__ s_rel, float* __restrict__ value_t,
        float* __restrict__ e_src, float* __restrict__ e_tgt) {
    __shared__ float xs[4][512];
    const int t = threadIdx.x;

    if (blockIdx.x < 2048) {
        // ---------------- srel ----------------
        const int lane = t & 63;
        const int wave = (blockIdx.x * 256 + t) >> 6;   // 0..8191

        float wrl[64];   // wrl[kk*8+h] = wr_eff[(lane*8+kk)*8+h]
        {
            const float4* wp = (const float4*)(wr_eff + lane * 64);
#pragma unroll
            for (int q = 0; q < 16; q++) {
                float4 v = wp[q];
                wrl[q * 4 + 0] = v.x; wrl[q * 4 + 1] = v.y;
                wrl[q * 4 + 2] = v.z; wrl[q * 4 + 3] = v.w;
            }
        }

        const bool hi32 = (lane & 32) != 0;
        const bool hi16 = (lane & 16) != 0;
        const bool hi8  = (lane & 8) != 0;
        const int  hsel = (lane >> 3) & 7;

#pragma unroll 2
        for (int it = 0; it < 16; ++it) {
            int row = wave + it * 8192;
            const float4* rp = (const float4*)(rel + (size_t)row * 512 + lane * 8);
            float4 u0 = rp[0];
            float4 u1 = rp[1];
            float x[8];
            x[0] = u0.x; x[1] = u0.y; x[2] = u0.z; x[3] = u0.w;
            x[4] = u1.x; x[5] = u1.y; x[6] = u1.z; x[7] = u1.w;
            float acc[8] = {0.f,0.f,0.f,0.f,0.f,0.f,0.f,0.f};
#pragma unroll
            for (int kk = 0; kk < 8; kk++)
#pragma unroll
                for (int h = 0; h < 8; h++)
                    acc[h] = fmaf(x[kk], wrl[kk * 8 + h], acc[h]);

            float a4[4];
#pragma unroll
            for (int hh = 0; hh < 4; hh++) {
                float send = hi32 ? acc[hh] : acc[hh + 4];
                float recv = __shfl_xor(send, 32, 64);
                float own  = hi32 ? acc[hh + 4] : acc[hh];
                a4[hh] = own + recv;
            }
            float a2[2];
#pragma unroll
            for (int hh = 0; hh < 2; hh++) {
                float send = hi16 ? a4[hh] : a4[hh + 2];
                float recv = __shfl_xor(send, 16, 64);
                float own  = hi16 ? a4[hh + 2] : a4[hh];
                a2[hh] = own + recv;
            }
            float send = hi8 ? a2[0] : a2[1];
            float recv = __shfl_xor(send, 8, 64);
            float a1 = (hi8 ? a2[1] : a2[0]) + recv;
            a1 += __shfl_xor(a1, 4, 64);
            a1 += __shfl_xor(a1, 2, 64);
            a1 += __shfl_xor(a1, 1, 64);

            if ((lane & 7) == 0) {
                float v = leaky(a1);
                int b = row >> 14, rem = row & 16383;
                s_rel[(((size_t)(b * 8 + hsel)) << 14) + rem] = v;
            }
        }
        return;
    }

    // ---------------- value GEMM ----------------
    const int row0 = (blockIdx.x - 2048) * 4;      // flat b*128+l
    {
        int r = t >> 6, seg = t & 63;
        const float4* ip = (const float4*)(inp + (size_t)(row0 + r) * 512 + seg * 8);
        float4 a = ip[0], bq = ip[1];
        *(float4*)&xs[r][seg * 8]     = a;
        *(float4*)&xs[r][seg * 8 + 4] = bq;
    }
    __syncthreads();
    const int c0 = t * 2;
    float acc[4][2] = {};
    for (int k0 = 0; k0 < 512; k0 += 4) {
        float4 xr[4];
#pragma unroll
        for (int r = 0; r < 4; r++) xr[r] = *(const float4*)&xs[r][k0];
#define VSTEP(COMP, I)                                                          \
        {                                                                       \
            float2 wv = *(const float2*)(Wv + (size_t)(k0 + I) * 512 + c0);     \
            _Pragma("unroll")                                                   \
            for (int r = 0; r < 4; r++) {                                       \
                acc[r][0] = fmaf(xr[r].COMP, wv.x, acc[r][0]);                  \
                acc[r][1] = fmaf(xr[r].COMP, wv.y, acc[r][1]);                  \
            }                                                                   \
        }
        VSTEP(x, 0) VSTEP(y, 1) VSTEP(z, 2) VSTEP(w, 3)
#undef VSTEP
    }
    const int h = t >> 5;
    const int d0 = c0 & 63;
    const int b = row0 >> 7, l0 = row0 & 127;
    {
        float4 v0 = make_float4(acc[0][0], acc[1][0], acc[2][0], acc[3][0]);
        float4 v1 = make_float4(acc[0][1], acc[1][1], acc[2][1], acc[3][1]);
        *(float4*)&value_t[((size_t)((b * 8 + h) * 64 + d0)) * 128 + l0] = v0;
        *(float4*)&value_t[((size_t)((b * 8 + h) * 64 + d0 + 1)) * 128 + l0] = v1;
    }
    float ws0 = wsrc[c0], ws1 = wsrc[c0 + 1];
    float wt0 = wtgt[c0], wt1 = wtgt[c0 + 1];
    float es[4], et[4];
#pragma unroll
    for (int r = 0; r < 4; r++) {
        es[r] = acc[r][0] * ws0 + acc[r][1] * ws1;
        et[r] = acc[r][0] * wt0 + acc[r][1] * wt1;
    }
#pragma unroll
    for (int off = 16; off >= 1; off >>= 1)
#pragma unroll
        for (int r = 0; r < 4; r++) {
            es[r] += __shfl_xor(es[r], off, 64);
            et[r] += __shfl_xor(et[r], off, 64);
        }
    if ((t & 31) == 0) {
#pragma unroll
        for (int r = 0; r < 4; r++) {
            e_src[(b * 8 + h) * 128 + l0 + r] = es[r];
            e_tgt[(b * 8 + h) * 128 + l0 + r] = et[r];
        }
    }
}

// ---------------------------------------------------------------------------
// K3: fused attn (both softmaxes + AV, all 8 heads) + final GEMM + residual.
// Block = (b, i-quad); wave w owns row i = iq*4+w across all heads (no
// inter-wave syncs in the attn phase), X rows accumulate in LDS, single
// __syncthreads, then the block does the final 4x512 GEMM for its rows.
// s_rel aliases out_ar (same-thread read-then-write per head).
// ---------------------------------------------------------------------------
__global__ __launch_bounds__(256) void k_attn_final(
        const float* s_rel, const float* __restrict__ value_t,
        const float* __restrict__ e_src, const float* __restrict__ e_tgt,
        const int* __restrict__ adj, const unsigned char* __restrict__ mask,
        const float* __restrict__ Wf, const float* __restrict__ bias,
        const float* __restrict__ inp,
        float* __restrict__ out_av, float* out_ar, float* __restrict__ outf) {
    __shared__ float xls[4][1024];
    __shared__ float lav[4][128];
    __shared__ float lar[4][128];
    const int t = threadIdx.x;
    const int lane = t & 63;
    const int w = t >> 6;
    const int b = blockIdx.x >> 5;         // 0..7
    const int iq = blockIdx.x & 31;
    const int i = iq * 4 + w;
    const int j0 = lane, j1 = lane + 64;

    const unsigned char m0 = mask[(size_t)(b * 128 + i) * 128 + j0];
    const unsigned char m1 = mask[(size_t)(b * 128 + i) * 128 + j1];

    for (int h = 0; h < 8; h++) {
        const int bh = b * 8 + h;
        const size_t rowbase = ((size_t)bh * 128 + i) * 128;
        const float etg = e_tgt[bh * 128 + i];

        float sv0 = leaky(etg + e_src[bh * 128 + j0]);
        float sv1 = leaky(etg + e_src[bh * 128 + j1]);
        float sr0 = s_rel[rowbase + j0];
        float sr1 = s_rel[rowbase + j1];
        int a0 = adj[rowbase + j0], a1 = adj[rowbase + j1];
        bool bad0 = m0 || (a0 == 0);
        bool bad1 = m1 || (a1 == 0);
        if (bad0) { sv0 = -1e30f; sr0 = -1e30f; }
        if (bad1) { sv1 = -1e30f; sr1 = -1e30f; }

        float mv = fmaxf(sv0, sv1), mr = fmaxf(sr0, sr1);
#pragma unroll
        for (int off = 32; off >= 1; off >>= 1) {
            mv = fmaxf(mv, __shfl_xor(mv, off, 64));
            mr = fmaxf(mr, __shfl_xor(mr, off, 64));
        }
        float pv0 = bad0 ? 0.f : __expf(sv0 - mv);
        float pv1 = bad1 ? 0.f : __expf(sv1 - mv);
        float pr0 = bad0 ? 0.f : __expf(sr0 - mr);
        float pr1 = bad1 ? 0.f : __expf(sr1 - mr);
        float sumv = pv0 + pv1, sumr = pr0 + pr1;
#pragma unroll
        for (int off = 32; off >= 1; off >>= 1) {
            sumv += __shfl_xor(sumv, off, 64);
            sumr += __shfl_xor(sumr, off, 64);
        }
        float iv = 1.f / fmaxf(sumv, 1e-12f);
        float ir = 1.f / fmaxf(sumr, 1e-12f);
        float av0 = pv0 * iv, av1 = pv1 * iv;
        float ar0 = pr0 * ir, ar1 = pr1 * ir;

        out_av[rowbase + j0] = av0;
        out_av[rowbase + j1] = av1;
        out_ar[rowbase + j0] = ar0;
        out_ar[rowbase + j1] = ar1;

        // wave-private LDS slice; written+read by wave w only (no barrier)
        lav[w][j0] = av0; lav[w][j1] = av1;
        lar[w][j0] = ar0; lar[w][j1] = ar1;

        const float4* vrow = (const float4*)(value_t + ((size_t)bh * 64 + lane) * 128);
        float accv = 0.f, accr = 0.f;
#pragma unroll 8
        for (int jb = 0; jb < 32; jb++) {
            float4 v4 = vrow[jb];
            float4 a4 = *(const float4*)&lav[w][jb * 4];
            float4 r4 = *(const float4*)&lar[w][jb * 4];
            accv = fmaf(a4.x, v4.x, accv); accv = fmaf(a4.y, v4.y, accv);
            accv = fmaf(a4.z, v4.z, accv); accv = fmaf(a4.w, v4.w, accv);
            accr = fmaf(r4.x, v4.x, accr); accr = fmaf(r4.y, v4.y, accr);
            accr = fmaf(r4.z, v4.z, accr); accr = fmaf(r4.w, v4.w, accr);
        }
        xls[w][h * 64 + lane] = accv;
        xls[w][512 + h * 64 + lane] = accr;
    }
    __syncthreads();

    // ---- final GEMM for rows row0..row0+3 (row0 = blockIdx.x*4) ----
    const int c0 = t * 2;
    float acc[4][2] = {};
    for (int k0 = 0; k0 < 1024; k0 += 4) {
        float4 xr[4];
#pragma unroll
        for (int r = 0; r < 4; r++) xr[r] = *(const float4*)&xls[r][k0];
#define FSTEP(COMP, I)                                                          \
        {                                                                       \
            float2 wv = *(const float2*)(Wf + (size_t)(k0 + I) * 512 + c0);     \
            _Pragma("unroll")                                                   \
            for (int r = 0; r < 4; r++) {                                       \
                acc[r][0] = fmaf(xr[r].COMP, wv.x, acc[r][0]);                  \
                acc[r][1] = fmaf(xr[r].COMP, wv.y, acc[r][1]);                  \
            }                                                                   \
        }
        FSTEP(x, 0) FSTEP(y, 1) FSTEP(z, 2) FSTEP(w, 3)
#undef FSTEP
    }
    const int row0 = blockIdx.x * 4;
    float b0 = bias[c0], b1 = bias[c0 + 1];
#pragma unroll
    for (int r = 0; r < 4; r++) {
        size_t ro = (size_t)(row0 + r) * 512;
        float2 ivl = *(const float2*)(inp + ro + c0);
        float v0 = acc[r][0] + b0 + ivl.x;
        float v1 = acc[r][1] + b1 + ivl.y;
        *(float2*)&outf[ro + c0] = make_float2(v0, v1);
    }
}

// ---------------------------------------------------------------------------
extern "C" void kernel_launch(void* const* d_in, const int* in_sizes, int n_in,
                              void* d_out, int out_size, void* d_ws, size_t ws_size,
                              hipStream_t stream) {
    const float* inp  = (const float*)d_in[0];
    const float* rel  = (const float*)d_in[1];
    const unsigned char* mask = (const unsigned char*)d_in[2];
    const int*   adj  = (const int*)d_in[3];
    const float* Wv   = (const float*)d_in[7];
    const float* Wr   = (const float*)d_in[8];
    const float* wsrc = (const float*)d_in[9];
    const float* wtgt = (const float*)d_in[10];
    const float* wrel = (const float*)d_in[11];
    const float* Wf   = (const float*)d_in[12];
    const float* bfin = (const float*)d_in[13];

    float* outf   = (float*)d_out;
    float* out_av = outf + (size_t)B_ * L_ * D_;                 // +524288
    float* out_ar = out_av + (size_t)B_ * H_ * L_ * L_;          // +1048576

    char* ws = (char*)d_ws;
    float* wr_eff  = (float*)(ws);                       // 16 KB
    float* value_t = (float*)(ws + 16384);               // 2 MB
    float* e_src   = (float*)(ws + 2113536);             // 32 KB
    float* e_tgt   = (float*)(ws + 2146304);             // 32 KB (ends ~2.1 MB)

    k_wreff<<<16, 256, 0, stream>>>(Wr, wrel, wr_eff);
    k_srel_value<<<2304, 256, 0, stream>>>(rel, wr_eff, inp, Wv, wsrc, wtgt,
                                           out_ar, value_t, e_src, e_tgt);
    k_attn_final<<<256, 256, 0, stream>>>(out_ar, value_t, e_src, e_tgt, adj, mask,
                                          Wf, bfin, inp, out_av, out_ar, outf);
}